// Round 1
// 415.173 us; speedup vs baseline: 1.0071x; 1.0071x over previous
//
#include <hip/hip_runtime.h>
#include <math.h>

// Problem constants
#define BB 4
#define TT 2048
#define CC 1024
#define HH 16
#define F3 3072          // 3*C
#define NTOK (BB*TT)     // 8192
#define KDIM 1024

typedef __attribute__((ext_vector_type(8))) short short8;            // 8 bf16
typedef __attribute__((ext_vector_type(8))) unsigned short ushort8;
typedef __attribute__((ext_vector_type(4))) unsigned short ushort4v;
typedef __attribute__((ext_vector_type(4))) float float4v;

static __device__ __forceinline__ unsigned short f2bf(float x) {
    union { float f; unsigned u; } v; v.f = x;
    unsigned r = v.u + 0x7fffu + ((v.u >> 16) & 1u);
    return (unsigned short)(r >> 16);
}
static __device__ __forceinline__ float bf2f(unsigned short h) {
    union { unsigned u; float f; } v; v.u = ((unsigned)h) << 16;
    return v.f;
}

// async 16B/lane global->LDS DMA; LDS dest = base + lane*16 (wave-uniform base)
static __device__ __forceinline__ void async16(const void* g, void* l) {
    __builtin_amdgcn_global_load_lds(
        (const __attribute__((address_space(1))) unsigned int*)g,
        (__attribute__((address_space(3))) unsigned int*)l, 16, 0, 0);
}

// DPP cross-lane (VALU pipe): ror8/ror4 + quad_perm xor2/xor1 = 16-lane butterfly
template <int C>
static __device__ __forceinline__ float dppf(float x) {
    return __int_as_float(
        __builtin_amdgcn_update_dpp(0, __float_as_int(x), C, 0xf, 0xf, true));
}
static __device__ __forceinline__ float red16_sum(float v) {
    v += dppf<0x128>(v);
    v += dppf<0x124>(v);
    v += dppf<0x4E>(v);
    v += dppf<0xB1>(v);
    return v;
}

#if __has_builtin(__builtin_amdgcn_exp2f)
#define EXP2(x) __builtin_amdgcn_exp2f(x)
#else
#define EXP2(x) __expf((x) * 0.6931471805599453f)
#endif

// ---------------------------------------------------------------------------
// prep_w: W[K,N] fp32 -> WtH/WtL [N][K] bf16 hi/lo (transpose + split).
// ---------------------------------------------------------------------------
__global__ __launch_bounds__(256) void prep_w(
    const float* __restrict__ W, unsigned short* __restrict__ WtH,
    unsigned short* __restrict__ WtL, int N)
{
    __shared__ float Ls[64][65];
    const int t = threadIdx.x;
    const int n0 = blockIdx.x * 64, k0 = blockIdx.y * 64;
    const int cc = t & 63, rr = t >> 6;
    #pragma unroll
    for (int i = 0; i < 16; ++i) {
        const int row = rr + 4 * i;
        Ls[row][cc] = W[(long)(k0 + row) * N + n0 + cc];
    }
    __syncthreads();
    const int n = t >> 2, seg = (t & 3) << 4;
    ushort8 h0, h1, l0, l1;
    #pragma unroll
    for (int j = 0; j < 8; ++j) {
        float x0 = Ls[seg + j][n];
        h0[j] = f2bf(x0); l0[j] = f2bf(x0 - bf2f(h0[j]));
        float x1 = Ls[seg + 8 + j][n];
        h1[j] = f2bf(x1); l1[j] = f2bf(x1 - bf2f(h1[j]));
    }
    const long o = (long)(n0 + n) * KDIM + k0 + seg;
    *(ushort8*)(WtH + o) = h0;     *(ushort8*)(WtH + o + 8) = h1;
    *(ushort8*)(WtL + o) = l0;     *(ushort8*)(WtL + o + 8) = l1;
}

// ---------------------------------------------------------------------------
// split_f32: X fp32 -> XH/XL bf16 hi/lo, elementwise.
// ---------------------------------------------------------------------------
__global__ __launch_bounds__(256) void split_f32(
    const float* __restrict__ X, unsigned short* __restrict__ XH,
    unsigned short* __restrict__ XL)
{
    const long i = (long)blockIdx.x * 256 + threadIdx.x;
    const float4 v = ((const float4*)X)[i];
    ushort4v h, lo;
    h[0] = f2bf(v.x); lo[0] = f2bf(v.x - bf2f(h[0]));
    h[1] = f2bf(v.y); lo[1] = f2bf(v.y - bf2f(h[1]));
    h[2] = f2bf(v.z); lo[2] = f2bf(v.z - bf2f(h[2]));
    h[3] = f2bf(v.w); lo[3] = f2bf(v.w - bf2f(h[3]));
    ((ushort4v*)XH)[i] = h;
    ((ushort4v*)XL)[i] = lo;
}

// ---------------------------------------------------------------------------
// gemm_split R11: out[M,N] = (AH+AL)[M,K] @ (BH+BL)^T[N,K] + bias, 3-term
// split-bf16 MFMA.
// 8-phase-style counted-vmcnt schedule (T3+T4+T5, per m196/m198/m218):
//  * BM=BN=128, BK=64 (2 k-slices of 32), 8 waves (512 thr), WARPS 4x2,
//    per-wave 32x64 output (acc[2][4]).
//  * LDS [2 dbuf][4 arr: AH,AL,BH,BL][2 ks][128x32 bf16] = 128 KiB.
//  * 4 phases per K-tile: {ds_read frags | 2 stage issues | barrier |
//    lgkmcnt(0) | setprio(1) 12xMFMA setprio(0) | barrier}.
//    Phase (ks,nh): A-frags read at nh=0, held in regs through nh=1.
//  * Counted vmcnt(8) at ph1/ph3 ends only (never 0 in main loop).
//    Issue pattern: tile t ph0/ph1 stage tile t+1 ks1 (buf^1);
//    ph2/ph3 stage tile t+2 ks0 (same buf: ks0 blocks freed after ph1).
//    Prologue = 12 issues (t0 ks0, t0 ks1, t1 ks0) + vmcnt(8).
//    Peeled tail: t=14 vmcnt(4), t=15 vmcnt(0).
//  * XOR-swizzled unpadded LDS identical to R9/R10 (0 conflicts measured):
//    stored_seg = (kseg + (row>>1)) & 3; inverse applied to global src.
//  * T1 bijective XCD swizzle on linear block id (nwg % 8 == 0 for both
//    launches: 1536, 512).
// ---------------------------------------------------------------------------
#define BAR()  asm volatile("s_barrier" ::: "memory")
#define LGK0() asm volatile("s_waitcnt lgkmcnt(0)" ::: "memory")
#define VMW(n) asm volatile("s_waitcnt vmcnt(" #n ")" ::: "memory")

#define STAGE_A(buf, kof, ks) do { \
    async16(aHs + (kof) + (ks) * 32, &LDS[buf][0][ks][ldst]); \
    async16(aLs + (kof) + (ks) * 32, &LDS[buf][1][ks][ldst]); } while (0)
#define STAGE_B(buf, kof, ks) do { \
    async16(bHs + (kof) + (ks) * 32, &LDS[buf][2][ks][ldst]); \
    async16(bLs + (kof) + (ks) * 32, &LDS[buf][3][ks][ldst]); } while (0)

#define READ_A(cur, ks) do { \
    _Pragma("unroll") for (int mt = 0; mt < 2; ++mt) { \
      const int off = (wm * 32 + mt * 16 + l) * 32 + swz; \
      fa_h[mt] = *(const short8*)&LDS[cur][0][ks][off]; \
      fa_l[mt] = *(const short8*)&LDS[cur][1][ks][off]; } } while (0)
#define READ_B(cur, ks, nh) do { \
    _Pragma("unroll") for (int j = 0; j < 2; ++j) { \
      const int off = (wn * 64 + ((nh) * 2 + j) * 16 + l) * 32 + swz; \
      fb_h[j] = *(const short8*)&LDS[cur][2][ks][off]; \
      fb_l[j] = *(const short8*)&LDS[cur][3][ks][off]; } } while (0)

#define MFMA3(nh) do { \
    _Pragma("unroll") for (int j = 0; j < 2; ++j) \
      _Pragma("unroll") for (int mt = 0; mt < 2; ++mt) { \
        acc[mt][(nh)*2+j] = __builtin_amdgcn_mfma_f32_16x16x32_bf16(fa_h[mt], fb_h[j], acc[mt][(nh)*2+j], 0, 0, 0); \
        acc[mt][(nh)*2+j] = __builtin_amdgcn_mfma_f32_16x16x32_bf16(fa_h[mt], fb_l[j], acc[mt][(nh)*2+j], 0, 0, 0); \
        acc[mt][(nh)*2+j] = __builtin_amdgcn_mfma_f32_16x16x32_bf16(fa_l[mt], fb_h[j], acc[mt][(nh)*2+j], 0, 0, 0); \
      } } while (0)

#define KTILE(cur, k1, k2, S1, S2, V1, V3) do { \
    /* ph0: ks=0 nh=0 */ \
    READ_A(cur, 0); READ_B(cur, 0, 0); \
    if (S1) STAGE_A((cur) ^ 1, k1, 1); \
    BAR(); LGK0(); \
    __builtin_amdgcn_s_setprio(1); MFMA3(0); __builtin_amdgcn_s_setprio(0); \
    BAR(); \
    /* ph1: ks=0 nh=1 */ \
    READ_B(cur, 0, 1); \
    if (S1) STAGE_B((cur) ^ 1, k1, 1); \
    BAR(); LGK0(); \
    __builtin_amdgcn_s_setprio(1); MFMA3(1); __builtin_amdgcn_s_setprio(0); \
    V1; BAR(); \
    /* ph2: ks=1 nh=0 */ \
    READ_A(cur, 1); READ_B(cur, 1, 0); \
    if (S2) STAGE_A(cur, k2, 0); \
    BAR(); LGK0(); \
    __builtin_amdgcn_s_setprio(1); MFMA3(0); __builtin_amdgcn_s_setprio(0); \
    BAR(); \
    /* ph3: ks=1 nh=1 */ \
    READ_B(cur, 1, 1); \
    if (S2) STAGE_B(cur, k2, 0); \
    BAR(); LGK0(); \
    __builtin_amdgcn_s_setprio(1); MFMA3(1); __builtin_amdgcn_s_setprio(0); \
    V3; BAR(); \
  } while (0)

__global__ __launch_bounds__(512, 2) void gemm_split(
    const unsigned short* __restrict__ AH, const unsigned short* __restrict__ AL,
    const unsigned short* __restrict__ BH, const unsigned short* __restrict__ BL,
    const float* __restrict__ bias, void* __restrict__ outp,
    unsigned short* __restrict__ VTp, int N, int mode)
{
    __shared__ __align__(16) unsigned short LDS[2][4][2][4096];   // 128 KiB

    const int tid = threadIdx.x;

    // T1: bijective XCD swizzle on the linear block id (nwg % 8 == 0).
    const int nbx = gridDim.x;
    const int nwg = nbx * gridDim.y;
    int lid = blockIdx.x + nbx * blockIdx.y;
    const int cpx = nwg >> 3;
    lid = (lid & 7) * cpx + (lid >> 3);
    const int n0 = (lid % nbx) * 128;
    const int m0 = (lid / nbx) * 128;

    const int lane = tid & 63, w = tid >> 6;
    const int wm = w >> 1, wn = w & 1;            // WARPS_M=4, WARPS_N=2
    const int l = lane & 15, quad = lane >> 4;
    const int swz = ((quad + (l >> 1)) & 3) * 8;  // read-side XOR swizzle

    // staging: thread tid covers row tid>>2, stored seg tid&3 of one
    // (arr, ks) 128x32 block; global kseg inverts the swizzle.
    const int srow = tid >> 2;
    const int kseg = ((tid & 3) - (tid >> 3)) & 3;
    const unsigned short* const aHs = AH + (long)(m0 + srow) * KDIM + kseg * 8;
    const unsigned short* const aLs = AL + (long)(m0 + srow) * KDIM + kseg * 8;
    const unsigned short* const bHs = BH + (long)(n0 + srow) * KDIM + kseg * 8;
    const unsigned short* const bLs = BL + (long)(n0 + srow) * KDIM + kseg * 8;
    const int ldst = tid * 8;   // == (tid>>2)*32 + (tid&3)*8

    float4v acc[2][4];
    #pragma unroll
    for (int mt = 0; mt < 2; ++mt)
        #pragma unroll
        for (int nt = 0; nt < 4; ++nt)
            acc[mt][nt] = (float4v){0.f, 0.f, 0.f, 0.f};
    short8 fa_h[2], fa_l[2], fb_h[2], fb_l[2];

    // prologue: tile0 ks0 (4), tile0 ks1 (4), tile1 ks0 (4) = 12 issues.
    STAGE_A(0, 0, 0); STAGE_B(0, 0, 0);
    STAGE_A(0, 0, 1); STAGE_B(0, 0, 1);
    STAGE_A(1, 64, 0); STAGE_B(1, 64, 0);
    VMW(8); BAR();          // tile0 ks0 landed on all waves

    // main loop: tiles 0..13 full pattern (NT = 16)
    #pragma unroll 1
    for (int t = 0; t < KDIM / 64 - 2; ++t) {
        const int cur = t & 1;
        const int k1 = (t + 1) * 64, k2 = (t + 2) * 64;
        KTILE(cur, k1, k2, 1, 1, VMW(8), VMW(8));
    }
    // t = 14: stage tile15 ks1 only; tighter tail waits
    KTILE(0, 960, 0, 1, 0, VMW(8), VMW(4));
    // t = 15: no staging; drain before ks1 reads
    KTILE(1, 0, 0, 0, 0, VMW(0), ((void)0));

    // epilogue
    #pragma unroll
    for (int nt = 0; nt < 4; ++nt) {
        const int col = n0 + wn * 64 + nt * 16 + l;
        const float bv = bias[col];
        if (mode == 0) {
            #pragma unroll
            for (int mt = 0; mt < 2; ++mt)
                #pragma unroll
                for (int i = 0; i < 4; ++i) {
                    const long row = m0 + wm * 32 + mt * 16 + quad * 4 + i;
                    ((float*)outp)[row * N + col] = acc[mt][nt][i] + bv;
                }
        } else if (col < 2048) {
            const float sc = (col < 1024) ? 0.18033688011112042f : 1.0f;  // 0.125*log2(e)
            #pragma unroll
            for (int mt = 0; mt < 2; ++mt)
                #pragma unroll
                for (int i = 0; i < 4; ++i) {
                    const long row = m0 + wm * 32 + mt * 16 + quad * 4 + i;
                    ((unsigned short*)outp)[row * N + col] = f2bf((acc[mt][nt][i] + bv) * sc);
                }
        } else {
            const int d = col & 63;
            const int hh = (col >> 6) - 32;
            const int bb = m0 >> 11;
            const long vtoff = ((long)(bb * HH + hh) * 64 + d) * TT;
            #pragma unroll
            for (int mt = 0; mt < 2; ++mt) {
                const int t0 = (m0 & 2047) + wm * 32 + mt * 16 + quad * 4;
                ushort4v pk;
                #pragma unroll
                for (int i = 0; i < 4; ++i) pk[i] = f2bf(acc[mt][nt][i] + bv);
                *(ushort4v*)(VTp + vtoff + t0) = pk;
            }
        }
    }
}

// ---------------------------------------------------------------------------
// Flash attention, bf16 MFMA (unchanged from R10: fixed-max softmax,
// truncation-consistent l accumulation, deferred 16-lane DPP reduction).
// ---------------------------------------------------------------------------
__global__ __attribute__((amdgpu_flat_work_group_size(256, 256),
                          amdgpu_waves_per_eu(4, 4)))
void attn_kernel(const unsigned short* __restrict__ qkv,
                 const unsigned short* __restrict__ VT,
                 unsigned short* __restrict__ yH,
                 unsigned short* __restrict__ yL)
{
    __shared__ __align__(16) unsigned short Qs[64 * 64];
    __shared__ __align__(16) unsigned short Ks[64 * 64];
    __shared__ __align__(16) unsigned short Vs[64 * 64];
    __shared__ __align__(16) unsigned short Ps[64 * 72];

    const int tid = threadIdx.x;
    const int q0 = blockIdx.x * 64;
    const int bh = blockIdx.y;
    const int b = bh >> 4;
    const int hoff = (bh & 15) * 64;
    const long base = (long)(b * TT);
    const long vtbase = (long)bh * 64 * TT;

    const int lane = tid & 63;
    const int wv = tid >> 6;
    const int l = lane & 15;
    const int quad = lane >> 4;
    const int qbase = wv * 16;
    const int xs = l & 7;

    const int u0 = (wv << 7) + lane, u1 = u0 + 64;
    const int r0 = u0 >> 3, s0 = (u0 & 7) ^ (r0 & 7);
    const int r1 = u1 >> 3, s1 = (u1 & 7) ^ (r1 & 7);

    async16(qkv + (base + q0 + r0) * F3 + hoff + s0 * 8, &Qs[u0 * 8]);
    async16(qkv + (base + q0 + r1) * F3 + hoff + s1 * 8, &Qs[u1 * 8]);

    float4v acc[4];
    #pragma unroll
    for (int dt = 0; dt < 4; ++dt) acc[dt] = (float4v){0.f, 0.f, 0.f, 0.f};
    float l_part[4] = {0.f, 0.f, 0.f, 0.f};   // per-lane partial sum of masked p

    for (int k0 = 0; k0 < TT; k0 += 64) {
        async16(qkv + (base + k0 + r0) * F3 + 1024 + hoff + s0 * 8, &Ks[u0 * 8]);
        async16(qkv + (base + k0 + r1) * F3 + 1024 + hoff + s1 * 8, &Ks[u1 * 8]);
        async16(VT + vtbase + (long)r0 * TT + k0 + s0 * 8, &Vs[u0 * 8]);
        async16(VT + vtbase + (long)r1 * TT + k0 + s1 * 8, &Vs[u1 * 8]);
        __syncthreads();

        // ---- S = Q K^T (exp2-domain scores; scale folded into Q) ----
        float4v sA[4];
        #pragma unroll
        for (int nt = 0; nt < 4; ++nt) sA[nt] = (float4v){0.f, 0.f, 0.f, 0.f};
        #pragma unroll
        for (int kit = 0; kit < 2; ++kit) {
            const int seg = ((kit * 4 + quad) ^ xs) * 8;
            const short8 qa = *(const short8*)&Qs[(qbase + l) * 64 + seg];
            #pragma unroll
            for (int nt = 0; nt < 4; ++nt) {
                const short8 kb = *(const short8*)&Ks[(16 * nt + l) * 64 + seg];
                sA[nt] = __builtin_amdgcn_mfma_f32_16x16x32_bf16(qa, kb, sA[nt], 0, 0, 0);
            }
        }

        // ---- softmax numerator: p = exp2(min(s,80)); truncate to bf16 for
        //      P, accumulate the MASKED value into l (exact normalization) ----
        #pragma unroll
        for (int nt = 0; nt < 4; ++nt) {
            #pragma unroll
            for (int i = 0; i < 4; ++i) {
                const float p = EXP2(fminf(sA[nt][i], 80.f));
                const unsigned pu = __float_as_uint(p);
                l_part[i] += __uint_as_float(pu & 0xFFFF0000u);
                Ps[(qbase + quad * 4 + i) * 72 + 16 * nt + l] =
                    (unsigned short)(pu >> 16);
            }
        }

        // ---- O += P V ----
        #pragma unroll
        for (int kit = 0; kit < 2; ++kit) {
            const short8 pa = *(const short8*)&Ps[(qbase + l) * 72 + kit * 32 + quad * 8];
            const int seg = ((kit * 4 + quad) ^ xs) * 8;
            #pragma unroll
            for (int dt = 0; dt < 4; ++dt) {
                const short8 vb = *(const short8*)&Vs[(16 * dt + l) * 64 + seg];
                acc[dt] = __builtin_amdgcn_mfma_f32_16x16x32_bf16(pa, vb, acc[dt], 0, 0, 0);
            }
        }
        __syncthreads();
    }

    // ---- one deferred 16-lane reduction, normalize, write y hi/lo ----
    #pragma unroll
    for (int i = 0; i < 4; ++i) {
        const float inv_l = 1.f / red16_sum(l_part[i]);
        const long row = base + q0 + qbase + quad * 4 + i;
        #pragma unroll
        for (int dt = 0; dt < 4; ++dt) {
            const float o = acc[dt][i] * inv_l;
            const unsigned short hh = f2bf(o);
            yH[row * CC + hoff + 16 * dt + l] = hh;
            yL[row * CC + hoff + 16 * dt + l] = f2bf(o - bf2f(hh));
        }
    }
}

extern "C" void kernel_launch(void* const* d_in, const int* in_sizes, int n_in,
                              void* d_out, int out_size, void* d_ws, size_t ws_size,
                              hipStream_t stream) {
    const float* x      = (const float*)d_in[0];
    const float* w_attn = (const float*)d_in[1];
    const float* b_attn = (const float*)d_in[2];
    const float* w_proj = (const float*)d_in[3];
    const float* b_proj = (const float*)d_in[4];
    float* out = (float*)d_out;

    // ws layout (bytes):
    // qkv 50.3MB | VT 16.8 | xyH 16.8 | xyL 16.8 | WaH 6.3 | WaL 6.3 |
    // WpH 2.1 | WpL 2.1  => ~117.5 MB
    char* wsb = (char*)d_ws;
    unsigned short* qkv = (unsigned short*)(wsb);
    unsigned short* VT  = (unsigned short*)(wsb + 50331648);
    unsigned short* xyH = (unsigned short*)(wsb + 67108864);
    unsigned short* xyL = (unsigned short*)(wsb + 83886080);
    unsigned short* WaH = (unsigned short*)(wsb + 100663296);
    unsigned short* WaL = (unsigned short*)(wsb + 106954752);
    unsigned short* WpH = (unsigned short*)(wsb + 113246208);
    unsigned short* WpL = (unsigned short*)(wsb + 115343360);

    // 0) weight transpose+split, x split
    prep_w<<<dim3(F3 / 64, KDIM / 64), 256, 0, stream>>>(w_attn, WaH, WaL, F3);
    prep_w<<<dim3(CC / 64, KDIM / 64), 256, 0, stream>>>(w_proj, WpH, WpL, CC);
    split_f32<<<(NTOK * CC / 4) / 256, 256, 0, stream>>>(x, xyH, xyL);

    // 1) qkv = x @ w_attn + b_attn  (Q scaled by 0.125*log2e, V -> VT)
    gemm_split<<<dim3(F3 / 128, NTOK / 128), 512, 0, stream>>>(
        xyH, xyL, WaH, WaL, b_attn, qkv, VT, F3, 1);

    // 2) attention -> y (bf16 hi/lo; overwrites x-split which is dead)
    attn_kernel<<<dim3(TT / 64, BB * HH), 256, 0, stream>>>(qkv, VT, xyH, xyL);

    // 3) out (fp32) = y @ w_proj + b_proj
    gemm_split<<<dim3(CC / 128, NTOK / 128), 512, 0, stream>>>(
        xyH, xyL, WpH, WpL, b_proj, out, (unsigned short*)nullptr, CC, 0);
}